// Round 3
// baseline (3752.583 us; speedup 1.0000x reference)
//
#include <hip/hip_runtime.h>

#define BB  1024
#define TT  128
#define HH1 512
#define HH2 256
#define CC  18
#define ROWB   1024               // bytes per W2T row
#define DUMMY1 (HH1 * ROWB)       // zeroed pad row of W2T
#define W3STR  (CC * 4)           // 72 B per W3T row
#define DUMMY2 (HH2 * W3STR)      // zeroed pad row of W3T

// d_ws layout (byte offsets)
#define WS_W2T   0                // (512+1) x 256 fp32 = 525312 B
#define WS_PAY   525312           // ring payload: 1024*128 slots * 16 B = 2 MB
#define WS_FLAGS 2622464          // 1024*128 u32 flags = 512 KB
#define WS_W3T   3146752          // (256+1) x 18 fp32 = 18504 B
#define FLAG_MAGIC 0x51C2D00Du    // != 0xAAAAAAAA poison

typedef float float2v __attribute__((ext_vector_type(2)));
typedef unsigned long long ull;

// Transpose W2 (256 x 512) -> W2T (512 x 256).
__global__ __launch_bounds__(256) void transpose_w2(const float* __restrict__ in,
                                                    float* __restrict__ out)
{
  __shared__ float tile[32][33];
  int bx = blockIdx.x * 32;            // h1
  int by = blockIdx.y * 32;            // h2
  int tx = threadIdx.x & 31;
  int ty = threadIdx.x >> 5;
#pragma unroll
  for (int j = 0; j < 32; j += 8)
    tile[ty + j][tx] = in[(by + ty + j) * HH1 + bx + tx];
  __syncthreads();
#pragma unroll
  for (int j = 0; j < 32; j += 8)
    out[(bx + ty + j) * HH2 + by + tx] = tile[tx][ty + j];
}

// Transpose W3 (18 x 256) -> W3T (257 x 18), with zeroed pad row 256.
__global__ __launch_bounds__(256) void transpose_w3(const float* __restrict__ in,
                                                    float* __restrict__ out)
{
  int tid = threadIdx.x;
  for (int i = tid; i < HH2 * CC; i += 256) {
    int h2 = i / CC, c = i - h2 * CC;
    out[i] = in[c * HH2 + h2];
  }
  if (tid < CC) out[HH2 * CC + tid] = 0.0f;
}

// Grid 2048: block = (row = idx>>1, half = idx&1). half 0 = consumer (cols
// 0..127 + layer3 + output), half 1 = producer (cols 128..255, streams s2
// masks one-way through a ring in d_ws). 256 threads = 4 waves.
__global__ __launch_bounds__(256) void snn_main(const float* __restrict__ x,
    const float* __restrict__ W1, const float* __restrict__ b1,
    const float* __restrict__ b2, const float* __restrict__ b3,
    char* __restrict__ ws, float* __restrict__ out)
{
  __shared__ float xrow[TT];
  __shared__ __align__(16) unsigned long long m1s[8];
  __shared__ __align__(16) unsigned long long m2s[2];
  __shared__ unsigned int list1[HH1 + 16];     // prescaled byte offsets
  __shared__ float partial[4 * 128];
  __shared__ unsigned int list2[HH2 + 8];      // consumer wave-0 private

  const int idx  = blockIdx.x;
  const int row  = idx >> 1;
  const int half = idx & 1;
  const int tid  = threadIdx.x;
  const int wv   = tid >> 6;
  const int lane = tid & 63;

  const float* W2T  = (const float*)(ws + WS_W2T);
  const char*  W3Tb = (const char*)(ws + WS_W3T);
  ull*      pay0  = (ull*)(ws + WS_PAY) + (size_t)row * TT * 2;
  unsigned* flag0 = (unsigned*)(ws + WS_FLAGS) + (size_t)row * TT;

  for (int i = tid; i < TT; i += 256) xrow[i] = x[row * TT + i];

  const float w1a = W1[tid], w1b = W1[tid + 256];
  const float b1a = b1[tid], b1b = b1[tid + 256];
  const float b2r = (tid < 128) ? b2[half * 128 + tid] : 0.0f;
  const int   j3  = (lane < 3 * CC) ? (lane / CC) : 0;
  const int   c3  = lane - ((lane < 3 * CC) ? j3 * CC : lane);
  const float b3r = (half == 0 && wv == 0 && lane < CC) ? b3[lane] : 0.0f;

  float v1a = 0.0f, v1b = 0.0f, v2 = 0.0f, v3 = 0.0f, acc = 0.0f;

  const char* gbase = (const char*)W2T + half * 512 + lane * 8;

  __syncthreads();

  for (int t = 0; t < TT; ++t) {
    float xt = xrow[t];

    // ---- layer 1 (bit-exact: mul-rn, add-rn, add-rn); identical in both halves
    float iA = __fadd_rn(__fmul_rn(xt, w1a), b1a);
    v1a = __fadd_rn(v1a, iA);
    bool sA = (v1a >= 1.0f);  v1a = sA ? (v1a - 1.0f) : v1a;
    float iB = __fadd_rn(__fmul_rn(xt, w1b), b1b);
    v1b = __fadd_rn(v1b, iB);
    bool sB = (v1b >= 1.0f);  v1b = sB ? (v1b - 1.0f) : v1b;
    unsigned long long mA = __ballot(sA);
    unsigned long long mB = __ballot(sB);
    if (lane == 0) { m1s[wv] = mA; m1s[4 + wv] = mB; }
    __syncthreads();                                   // A: m1 ready

    // ---- active-h1 list build (parallel mbcnt compaction) ----
    unsigned long long mw[8];
#pragma unroll
    for (int k = 0; k < 8; ++k) mw[k] = m1s[k];
    int base[8]; int cnt1 = 0;
#pragma unroll
    for (int k = 0; k < 8; ++k) { base[k] = cnt1; cnt1 += (int)__popcll(mw[k]); }
#pragma unroll
    for (int q = 0; q < 2; ++q) {
      int k = 2 * wv + q;
      unsigned long long m = mw[k];
      if ((m >> lane) & 1ull) {
        int rank = __builtin_amdgcn_mbcnt_hi((unsigned)(m >> 32),
                   __builtin_amdgcn_mbcnt_lo((unsigned)m, 0u));
        list1[base[k] + rank] = (unsigned)((k * 64 + lane) * ROWB);
      }
    }
    int rcnt1 = (cnt1 + 15) & ~15;
    if (tid < rcnt1 - cnt1) list1[cnt1 + tid] = (unsigned)DUMMY1;
    __syncthreads();                                   // B: list1 ready

    // ---- layer-2 gather: wave wv takes terms 4k+wv; lane covers cols 2l,2l+1
    float2v s2v = {0.0f, 0.0f};
    const int K = rcnt1 >> 2;
    for (int k = 0; k < K; k += 4) {
      unsigned o0 = list1[((k + 0) << 2) + wv];
      unsigned o1 = list1[((k + 1) << 2) + wv];
      unsigned o2 = list1[((k + 2) << 2) + wv];
      unsigned o3 = list1[((k + 3) << 2) + wv];
      float2v f0 = *(const float2v*)(gbase + o0);
      float2v f1 = *(const float2v*)(gbase + o1);
      float2v f2 = *(const float2v*)(gbase + o2);
      float2v f3 = *(const float2v*)(gbase + o3);
      s2v += f0; s2v += f1; s2v += f2; s2v += f3;
    }
    *(float2v*)&partial[wv * 128 + lane * 2] = s2v;
    __syncthreads();                                   // C: partials ready

    // ---- v2 / spike for this half's 128 cols (threads 0..127 = waves 0,1)
    if (tid < 128) {
      float d2 = __fadd_rn(__fadd_rn(__fadd_rn(partial[tid], partial[128 + tid]),
                                     partial[256 + tid]), partial[384 + tid]);
      float i2 = __fadd_rn(d2, b2r);
      v2 = __fadd_rn(v2, i2);
      bool s2 = (v2 >= 1.0f);  v2 = s2 ? (v2 - 1.0f) : v2;
      unsigned long long mW = __ballot(s2);
      if (lane == 0) m2s[wv] = mW;
    }
    __syncthreads();                                   // D: m2 ready

    if (half == 1) {
      // ---- producer: publish s2 mask (cols 128..255) ----
      if (tid == 0) {
        ull w0 = m2s[0], w1 = m2s[1];
        ull* p = pay0 + t * 2;
        p[0] = w0; p[1] = w1;
        __hip_atomic_store(flag0 + t, FLAG_MAGIC,
                           __ATOMIC_RELEASE, __HIP_MEMORY_SCOPE_AGENT);
      }
    } else if (wv == 0) {
      // ---- consumer wave 0: merge masks, layer 3 ----
      unsigned f;
      do {
        f = __hip_atomic_load(flag0 + t, __ATOMIC_ACQUIRE,
                              __HIP_MEMORY_SCOPE_AGENT);
        if (f != FLAG_MAGIC) __builtin_amdgcn_s_sleep(4);
      } while (f != FLAG_MAGIC);
      const ull* p = pay0 + t * 2;
      ull n0 = m2s[0], n1 = m2s[1], n2 = p[0], n3 = p[1];

      ull nn[4] = {n0, n1, n2, n3};
      int bas2[4]; int cnt2 = 0;
#pragma unroll
      for (int k = 0; k < 4; ++k) { bas2[k] = cnt2; cnt2 += (int)__popcll(nn[k]); }
#pragma unroll
      for (int k = 0; k < 4; ++k) {
        unsigned long long m = nn[k];
        if ((m >> lane) & 1ull) {
          int rank = __builtin_amdgcn_mbcnt_hi((unsigned)(m >> 32),
                     __builtin_amdgcn_mbcnt_lo((unsigned)m, 0u));
          list2[bas2[k] + rank] = (unsigned)((k * 64 + lane) * W3STR);
        }
      }
      int rcnt2 = cnt2 + ((3 - (cnt2 % 3)) % 3);       // pad to x3
      if (lane < rcnt2 - cnt2) list2[cnt2 + lane] = (unsigned)DUMMY2;
      __builtin_amdgcn_wave_barrier();
      __builtin_amdgcn_s_waitcnt(0xc07f);              // lgkmcnt(0)
      __builtin_amdgcn_wave_barrier();

      float d3 = 0.0f;
      if (lane < 3 * CC) {                             // lane = j3*18 + c3
        for (int k = 0; k < rcnt2; k += 3) {
          unsigned o = list2[k + j3];
          d3 = __fadd_rn(d3, *(const float*)(W3Tb + o + c3 * 4));
        }
      }
      float dA = __shfl(d3, lane + 18);
      float dB = __shfl(d3, lane + 36);
      if (lane < CC) {
        float tot = __fadd_rn(__fadd_rn(d3, dA), dB);
        float i3  = __fadd_rn(tot, b3r);
        v3 = __fadd_rn(v3, i3);
        bool s3 = (v3 >= 1.0f);  v3 = s3 ? (v3 - 1.0f) : v3;
        acc = __fadd_rn(acc, s3 ? 1.0f : 0.0f);
      }
    }
  }

  if (half == 0 && wv == 0 && lane < CC) out[row * CC + lane] = acc * (1.0f / TT);
}

extern "C" void kernel_launch(void* const* d_in, const int* in_sizes, int n_in,
                              void* d_out, int out_size, void* d_ws, size_t ws_size,
                              hipStream_t stream)
{
  (void)in_sizes; (void)n_in; (void)out_size; (void)ws_size;
  const float* x  = (const float*)d_in[0];
  const float* W1 = (const float*)d_in[1];
  const float* b1 = (const float*)d_in[2];
  const float* W2 = (const float*)d_in[3];
  const float* b2 = (const float*)d_in[4];
  const float* W3 = (const float*)d_in[5];
  const float* b3 = (const float*)d_in[6];
  // d_in[7] = repeat (structurally 1 for this problem shape)
  float* out = (float*)d_out;
  char*  ws  = (char*)d_ws;

  float* W2T = (float*)(ws + WS_W2T);
  float* W3T = (float*)(ws + WS_W3T);

  // zero the dummy pad row of W2T (row 512)
  hipMemsetAsync(W2T + (size_t)HH1 * HH2, 0, HH2 * sizeof(float), stream);

  dim3 tg(HH1 / 32, HH2 / 32);
  transpose_w2<<<tg, 256, 0, stream>>>(W2, W2T);
  transpose_w3<<<1, 256, 0, stream>>>(W3, W3T);

  snn_main<<<2 * BB, 256, 0, stream>>>(x, W1, b1, b2, b3, ws, out);
}

// Round 4
// 363.174 us; speedup vs baseline: 10.3327x; 10.3327x over previous
//
#include <hip/hip_runtime.h>
#include <cmath>

#define BB  1024
#define TT  128
#define HH1 512
#define HH2 256
#define CC  18
#define TCHUNK 32
#define NCHUNK (TT / TCHUNK)

#define W3STR  (CC * 4)           // 72 B per w3t row
#define DUMMY2 (HH2 * W3STR)      // zeroed pad row of w3t

// d_ws layout (byte offsets)
#define WS_DIG  0ull              // 8x4x16x2x32x16 i8 = 512 KB
#define WS_MASK 524288ull         // masks[t][row][8 u64] = 8 MB
#define WS_D2   8912896ull        // D2[tc<32][row][col] fp32 = 33.55 MB
#define WS_V2   42467328ull       // v2 state 1024x256 fp32 = 1 MB
#define WS_V3   43515904ull       // v3 state 1024x18 fp32
#define WS_ACC  43589632ull       // acc state 1024x18 fp32   (total ~43.7 MB)

typedef int  v4i  __attribute__((ext_vector_type(4)));
typedef int  v16i __attribute__((ext_vector_type(16)));
typedef unsigned long long ull;

// ---- prep: W2 fp32 -> 4 signed-i8 digit planes of round(w*2^32), laid out as
// [stripe(8)][d(4)][s(16)][h(2)][n(32)][j(16)] so a stripe slab (64 KB) is the
// exact LDS image phase_gemm wants. h1 = s*32 + h*16 + j ; h2 = stripe*32 + n.
__global__ __launch_bounds__(256) void prep_digits(const float* __restrict__ W2,
                                                   signed char* __restrict__ out)
{
  int i = blockIdx.x * 256 + threadIdx.x;         // [0, 524288)
  int j = i & 15, n = (i >> 4) & 31, h = (i >> 9) & 1;
  int s = (i >> 10) & 15, d = (i >> 14) & 3, st = i >> 16;
  int h1 = s * 32 + h * 16 + j;
  int h2 = st * 32 + n;
  float w = W2[h2 * HH1 + h1];
  long long ll = llrint((double)w * 4294967296.0);   // exact: |w|<0.045 -> |ll|<2^28
  int v = (int)ll;
  signed char d0 = (signed char)(v & 255); v = (v - d0) >> 8;
  signed char d1 = (signed char)(v & 255); v = (v - d1) >> 8;
  signed char d2 = (signed char)(v & 255); v = (v - d2) >> 8;
  signed char d3 = (signed char)v;                   // |d3| <= 12
  signed char dig = (d == 0) ? d0 : (d == 1) ? d1 : (d == 2) ? d2 : d3;
  out[i] = dig;
}

// ---- phase A: bit-exact layer-1 spike masks for all (row,t). One block/row.
__global__ __launch_bounds__(256) void phase_s1(const float* __restrict__ x,
    const float* __restrict__ W1, const float* __restrict__ b1,
    ull* __restrict__ masks)
{
  __shared__ float xrow[TT];
  int row = blockIdx.x, tid = threadIdx.x, wv = tid >> 6, lane = tid & 63;
  for (int i = tid; i < TT; i += 256) xrow[i] = x[row * TT + i];
  const float w1a = W1[tid], w1b = W1[tid + 256];
  const float b1a = b1[tid], b1b = b1[tid + 256];
  float v1a = 0.f, v1b = 0.f;
  __syncthreads();
  for (int t = 0; t < TT; ++t) {
    float xt = xrow[t];
    float iA = __fadd_rn(__fmul_rn(xt, w1a), b1a);
    v1a = __fadd_rn(v1a, iA);
    bool sA = (v1a >= 1.0f);  v1a = sA ? (v1a - 1.0f) : v1a;
    float iB = __fadd_rn(__fmul_rn(xt, w1b), b1b);
    v1b = __fadd_rn(v1b, iB);
    bool sB = (v1b >= 1.0f);  v1b = sB ? (v1b - 1.0f) : v1b;
    ull mA = __ballot(sA);
    ull mB = __ballot(sB);
    if (lane == 0) {
      ull* p = masks + ((size_t)t * BB + row) * 8;
      p[wv] = mA; p[4 + wv] = mB;
    }
  }
}

// ---- phase B: per t, D2 = S1 @ W2^T via 4 exact i8 digit planes.
// grid 512 = tsub(8) x rowtile(8) x stripe(8). Block: 4 waves, each a 32-row
// stripe of a 128x32 tile; B slab (64 KB) LDS-resident; A unpacked from mask
// bits in-register (3 VALU/dword). acc: 4 independent i32 MFMA chains.
__global__ __launch_bounds__(256) void phase_gemm(const signed char* __restrict__ Bd,
    const ull* __restrict__ masks, float* __restrict__ D2, int t0)
{
  __shared__ __align__(16) signed char Bl[65536];
  const int bid = blockIdx.x;
  const int stripe = bid & 7, rowtile = (bid >> 3) & 7, tsub = bid >> 6;
  const int tid = threadIdx.x, lane = tid & 63, wv = tid >> 6;
  const int half = lane >> 5;

  {
    const uint4* src = (const uint4*)(Bd + (size_t)stripe * 65536);
    uint4* dst = (uint4*)Bl;
    for (int i = tid; i < 4096; i += 256) dst[i] = src[i];
  }
  __syncthreads();

  const int arow   = rowtile * 128 + wv * 32 + (lane & 31);  // A row this lane feeds
  const int colbase = stripe * 32 + (lane & 31);
  const signed char* bbase = Bl + half * 512 + (lane & 31) * 16;
  const int hsh = half * 16;

  for (int tt = 0; tt < 4; ++tt) {
    const int tc = tsub * 4 + tt;                  // [0,32)
    const int t  = t0 + tc;
    const ull* mp = masks + ((size_t)t * BB + arow) * 8;
    ull words[8];
#pragma unroll
    for (int k = 0; k < 8; ++k) words[k] = mp[k];

    v16i acc0 = {0,0,0,0,0,0,0,0,0,0,0,0,0,0,0,0};
    v16i acc1 = {0,0,0,0,0,0,0,0,0,0,0,0,0,0,0,0};
    v16i acc2 = {0,0,0,0,0,0,0,0,0,0,0,0,0,0,0,0};
    v16i acc3 = {0,0,0,0,0,0,0,0,0,0,0,0,0,0,0,0};

#pragma unroll
    for (int s = 0; s < 16; ++s) {
      unsigned bits = (unsigned)(words[s >> 1] >> (((s & 1) << 5) + hsh)) & 0xFFFFu;
      v4i a;
      a.x = (int)((( bits        & 15u) * 0x204081u) & 0x01010101u);
      a.y = (int)((((bits >>  4) & 15u) * 0x204081u) & 0x01010101u);
      a.z = (int)((((bits >>  8) & 15u) * 0x204081u) & 0x01010101u);
      a.w = (int)((((bits >> 12) & 15u) * 0x204081u) & 0x01010101u);
      v4i b0 = *(const v4i*)(bbase + ( 0 * 32 + s * 2) * 512);
      v4i b1 = *(const v4i*)(bbase + ( 1 * 32 + s * 2) * 512);
      v4i b2 = *(const v4i*)(bbase + ( 2 * 32 + s * 2) * 512);
      v4i b3 = *(const v4i*)(bbase + ( 3 * 32 + s * 2) * 512);
      acc0 = __builtin_amdgcn_mfma_i32_32x32x32_i8(a, b0, acc0, 0, 0, 0);
      acc1 = __builtin_amdgcn_mfma_i32_32x32x32_i8(a, b1, acc1, 0, 0, 0);
      acc2 = __builtin_amdgcn_mfma_i32_32x32x32_i8(a, b2, acc2, 0, 0, 0);
      acc3 = __builtin_amdgcn_mfma_i32_32x32x32_i8(a, b3, acc3, 0, 0, 0);
    }

    // epilogue: exact int64 recombine -> correctly-rounded fp32
#pragma unroll
    for (int r = 0; r < 16; ++r) {
      long long ssum = (long long)acc0[r] + ((long long)acc1[r] << 8)
                     + ((long long)acc2[r] << 16) + ((long long)acc3[r] << 24);
      float d2v = (float)((double)ssum * (1.0 / 4294967296.0));
      int rowl = (r & 3) + 8 * (r >> 2) + 4 * half;          // verified C/D map
      int grow = rowtile * 128 + wv * 32 + rowl;
      D2[((size_t)tc * BB + grow) * HH2 + colbase] = d2v;
    }
  }
}

// ---- phase C: sequential v2 scan over the chunk + layer 3 + output.
__global__ __launch_bounds__(256) void phase_scan(const float* __restrict__ D2,
    const float* __restrict__ b2, const float* __restrict__ W3,
    const float* __restrict__ b3, float* __restrict__ v2ws,
    float* __restrict__ v3ws, float* __restrict__ accws,
    float* __restrict__ out, int t0)
{
  __shared__ float w3t[(HH2 + 1) * CC];
  __shared__ __align__(16) ull m2s[4];
  __shared__ unsigned list2[HH2 + 8];
  const int row = blockIdx.x, tid = threadIdx.x, wv = tid >> 6, lane = tid & 63;

  for (int i = tid; i < HH2 * CC; i += 256) {
    int c = i >> 8, h2 = i & 255;                   // W3 is [c][h2]
    w3t[h2 * CC + c] = W3[i];
  }
  if (tid < CC) w3t[HH2 * CC + tid] = 0.0f;

  const float b2r = b2[tid];
  const int j3 = (lane < 3 * CC) ? (lane / CC) : 0;
  const int c3 = lane - ((lane < 3 * CC) ? j3 * CC : lane);
  const bool first = (t0 == 0), last = (t0 == TT - TCHUNK);

  float v2 = first ? 0.f : v2ws[row * HH2 + tid];
  float v3 = 0.f, acc = 0.f, b3r = 0.f;
  if (wv == 0 && lane < CC) {
    b3r = b3[lane];
    if (!first) { v3 = v3ws[row * CC + lane]; acc = accws[row * CC + lane]; }
  }
  __syncthreads();

  float d2 = D2[((size_t)0 * BB + row) * HH2 + tid];
  for (int tc = 0; tc < TCHUNK; ++tc) {
    int tn = (tc + 1 < TCHUNK) ? tc + 1 : tc;
    float d2n = D2[((size_t)tn * BB + row) * HH2 + tid];   // prefetch

    float i2 = __fadd_rn(d2, b2r);
    v2 = __fadd_rn(v2, i2);
    bool s2 = (v2 >= 1.0f);  v2 = s2 ? (v2 - 1.0f) : v2;
    ull mW = __ballot(s2);
    if (lane == 0) m2s[wv] = mW;
    __syncthreads();

    if (wv == 0) {
      ull nn[4] = {m2s[0], m2s[1], m2s[2], m2s[3]};
      int bas2[4]; int cnt2 = 0;
#pragma unroll
      for (int k = 0; k < 4; ++k) { bas2[k] = cnt2; cnt2 += (int)__popcll(nn[k]); }
#pragma unroll
      for (int k = 0; k < 4; ++k) {
        ull m = nn[k];
        if ((m >> lane) & 1ull) {
          int rank = __builtin_amdgcn_mbcnt_hi((unsigned)(m >> 32),
                     __builtin_amdgcn_mbcnt_lo((unsigned)m, 0u));
          list2[bas2[k] + rank] = (unsigned)((k * 64 + lane) * W3STR);
        }
      }
      int rcnt2 = cnt2 + ((3 - (cnt2 % 3)) % 3);           // pad to x3
      if (lane < rcnt2 - cnt2) list2[cnt2 + lane] = (unsigned)DUMMY2;
      __builtin_amdgcn_wave_barrier();
      __builtin_amdgcn_s_waitcnt(0xc07f);                  // lgkmcnt(0)
      __builtin_amdgcn_wave_barrier();

      float d3 = 0.0f;
      if (lane < 3 * CC) {
        for (int k = 0; k < rcnt2; k += 3) {
          unsigned o = list2[k + j3];
          d3 = __fadd_rn(d3, *(const float*)((const char*)w3t + o + c3 * 4));
        }
      }
      float dA = __shfl(d3, lane + 18);
      float dB = __shfl(d3, lane + 36);
      if (lane < CC) {
        float tot = __fadd_rn(__fadd_rn(d3, dA), dB);
        float i3  = __fadd_rn(tot, b3r);
        v3 = __fadd_rn(v3, i3);
        bool s3 = (v3 >= 1.0f);  v3 = s3 ? (v3 - 1.0f) : v3;
        acc = __fadd_rn(acc, s3 ? 1.0f : 0.0f);
      }
    }
    __syncthreads();
    d2 = d2n;
  }

  v2ws[row * HH2 + tid] = v2;
  if (wv == 0 && lane < CC) {
    v3ws[row * CC + lane] = v3;
    accws[row * CC + lane] = acc;
    if (last) out[row * CC + lane] = acc * (1.0f / TT);
  }
}

extern "C" void kernel_launch(void* const* d_in, const int* in_sizes, int n_in,
                              void* d_out, int out_size, void* d_ws, size_t ws_size,
                              hipStream_t stream)
{
  (void)in_sizes; (void)n_in; (void)out_size; (void)ws_size;
  const float* x  = (const float*)d_in[0];
  const float* W1 = (const float*)d_in[1];
  const float* b1 = (const float*)d_in[2];
  const float* W2 = (const float*)d_in[3];
  const float* b2 = (const float*)d_in[4];
  const float* W3 = (const float*)d_in[5];
  const float* b3 = (const float*)d_in[6];
  // d_in[7] = repeat (structurally 1 for this problem shape)
  float* out = (float*)d_out;
  char*  ws  = (char*)d_ws;

  signed char* dig   = (signed char*)(ws + WS_DIG);
  ull*         masks = (ull*)(ws + WS_MASK);
  float*       D2    = (float*)(ws + WS_D2);
  float*       v2ws  = (float*)(ws + WS_V2);
  float*       v3ws  = (float*)(ws + WS_V3);
  float*       accws = (float*)(ws + WS_ACC);

  prep_digits<<<2048, 256, 0, stream>>>(W2, dig);
  phase_s1<<<1024, 256, 0, stream>>>(x, W1, b1, masks);
  for (int c = 0; c < NCHUNK; ++c) {
    phase_gemm<<<512, 256, 0, stream>>>(dig, masks, D2, c * TCHUNK);
    phase_scan<<<1024, 256, 0, stream>>>(D2, b2, W3, b3, v2ws, v3ws, accws,
                                         out, c * TCHUNK);
  }
}

// Round 5
// 331.450 us; speedup vs baseline: 11.3217x; 1.0957x over previous
//
#include <hip/hip_runtime.h>
#include <cmath>

#define BB  1024
#define TT  128
#define HH1 512
#define HH2 256
#define CC  18

#define W3STR  (CC * 4)           // 72 B per w3t row
#define DUMMY2 (HH2 * W3STR)      // zeroed pad row of w3t

// d_ws layout (byte offsets); ws_size ~256 MiB (fill evidence R4)
#define WS_DIG  0ull              // 8x4x16x2x32x16 i8 = 512 KB
#define WS_MASK 524288ull         // masks[t][row][8 u64] = 8 MB
#define WS_D2   8912896ull        // D2[t<128][row][col] fp32 = 134.2 MB (end ~143 MB)

typedef int  v4i  __attribute__((ext_vector_type(4)));
typedef int  v16i __attribute__((ext_vector_type(16)));
typedef unsigned long long ull;

// ---- prep: W2 fp32 -> 4 signed-i8 digit planes of llrint(w*2^32), laid out
// [stripe(8)][d(4)][s(16)][h(2)][n(32)][j(16)]; h1 = s*32+h*16+j, h2 = stripe*32+n.
__global__ __launch_bounds__(256) void prep_digits(const float* __restrict__ W2,
                                                   signed char* __restrict__ out)
{
  int i = blockIdx.x * 256 + threadIdx.x;         // [0, 524288)
  int j = i & 15, n = (i >> 4) & 31, h = (i >> 9) & 1;
  int s = (i >> 10) & 15, d = (i >> 14) & 3, st = i >> 16;
  int h1 = s * 32 + h * 16 + j;
  int h2 = st * 32 + n;
  float w = W2[h2 * HH1 + h1];
  long long ll = llrint((double)w * 4294967296.0);
  int v = (int)ll;
  signed char d0 = (signed char)(v & 255); v = (v - d0) >> 8;
  signed char d1 = (signed char)(v & 255); v = (v - d1) >> 8;
  signed char d2 = (signed char)(v & 255); v = (v - d2) >> 8;
  signed char d3 = (signed char)v;
  signed char dig = (d == 0) ? d0 : (d == 1) ? d1 : (d == 2) ? d2 : d3;
  out[i] = dig;
}

// ---- phase A: bit-exact layer-1 spike masks for all (row,t). One block/row.
__global__ __launch_bounds__(256) void phase_s1(const float* __restrict__ x,
    const float* __restrict__ W1, const float* __restrict__ b1,
    ull* __restrict__ masks)
{
  __shared__ float xrow[TT];
  int row = blockIdx.x, tid = threadIdx.x, wv = tid >> 6, lane = tid & 63;
  for (int i = tid; i < TT; i += 256) xrow[i] = x[row * TT + i];
  const float w1a = W1[tid], w1b = W1[tid + 256];
  const float b1a = b1[tid], b1b = b1[tid + 256];
  float v1a = 0.f, v1b = 0.f;
  __syncthreads();
  for (int t = 0; t < TT; ++t) {
    float xt = xrow[t];
    float iA = __fadd_rn(__fmul_rn(xt, w1a), b1a);
    v1a = __fadd_rn(v1a, iA);
    bool sA = (v1a >= 1.0f);  v1a = sA ? (v1a - 1.0f) : v1a;
    float iB = __fadd_rn(__fmul_rn(xt, w1b), b1b);
    v1b = __fadd_rn(v1b, iB);
    bool sB = (v1b >= 1.0f);  v1b = sB ? (v1b - 1.0f) : v1b;
    ull mA = __ballot(sA);
    ull mB = __ballot(sB);
    if (lane == 0) {
      ull* p = masks + ((size_t)t * BB + row) * 8;
      p[wv] = mA; p[4 + wv] = mB;
    }
  }
}

// ---- phase B: D2[t] = S1[t] @ W2^T, exact via 4 i8 digit planes.
// grid 2048 = tsub(32) x rowtile(8) x stripe(8); block covers 128 rows x 32
// cols x 4 t. Two digit-pair passes reuse each B fragment across 4 t:
// 64 ds_read_b128 : 256 MFMA per wave (was 1:1 in R4).
__global__ __launch_bounds__(256, 1) void phase_gemm(const signed char* __restrict__ Bd,
    const ull* __restrict__ masks, float* __restrict__ D2)
{
  __shared__ __align__(16) signed char Bl[65536];
  const int bid = blockIdx.x;
  const int stripe = bid & 7, rowtile = (bid >> 3) & 7, tsub = bid >> 6; // [0,32)
  const int tid = threadIdx.x, lane = tid & 63, wv = tid >> 6;
  const int half = lane >> 5;

  {
    const uint4* src = (const uint4*)(Bd + (size_t)stripe * 65536);
    uint4* dst = (uint4*)Bl;
#pragma unroll
    for (int i = 0; i < 16; ++i) dst[tid + 256 * i] = src[tid + 256 * i];
  }

  const int arow    = rowtile * 128 + wv * 32 + (lane & 31);
  const int colbase = stripe * 32 + (lane & 31);
  const int hsh     = half * 16;
  const signed char* bbase = Bl + half * 512 + (lane & 31) * 16;

  // mask words for this lane's row, 4 timesteps
  ull words[4][8];
#pragma unroll
  for (int tt = 0; tt < 4; ++tt) {
    const ull* mp = masks + ((size_t)(tsub * 4 + tt) * BB + arow) * 8;
#pragma unroll
    for (int k = 0; k < 8; ++k) words[tt][k] = mp[k];
  }
  __syncthreads();

  float slo[4][16];
#pragma unroll
  for (int p = 0; p < 2; ++p) {
    v16i accL[4], accH[4];
#pragma unroll
    for (int tt = 0; tt < 4; ++tt) {
      accL[tt] = (v16i){0,0,0,0,0,0,0,0,0,0,0,0,0,0,0,0};
      accH[tt] = (v16i){0,0,0,0,0,0,0,0,0,0,0,0,0,0,0,0};
    }
#pragma unroll
    for (int s = 0; s < 16; ++s) {
      v4i bL = *(const v4i*)(bbase + ((2 * p)     * 16 + s) * 1024);
      v4i bH = *(const v4i*)(bbase + ((2 * p + 1) * 16 + s) * 1024);
#pragma unroll
      for (int tt = 0; tt < 4; ++tt) {
        unsigned bits = (unsigned)(words[tt][s >> 1] >> (((s & 1) << 5) + hsh)) & 0xFFFFu;
        v4i a;
        a.x = (int)((( bits        & 15u) * 0x204081u) & 0x01010101u);
        a.y = (int)((((bits >>  4) & 15u) * 0x204081u) & 0x01010101u);
        a.z = (int)((((bits >>  8) & 15u) * 0x204081u) & 0x01010101u);
        a.w = (int)((((bits >> 12) & 15u) * 0x204081u) & 0x01010101u);
        accL[tt] = __builtin_amdgcn_mfma_i32_32x32x32_i8(a, bL, accL[tt], 0, 0, 0);
        accH[tt] = __builtin_amdgcn_mfma_i32_32x32x32_i8(a, bH, accH[tt], 0, 0, 0);
      }
    }
    if (p == 0) {
      // exact integer fold: |acc0 + 256*acc1| < 2^24 -> exact fp32
#pragma unroll
      for (int tt = 0; tt < 4; ++tt)
#pragma unroll
        for (int r = 0; r < 16; ++r)
          slo[tt][r] = (float)(accL[tt][r] + 256 * accH[tt][r]);
    } else {
#pragma unroll
      for (int tt = 0; tt < 4; ++tt) {
#pragma unroll
        for (int r = 0; r < 16; ++r) {
          float shi = (float)(accL[tt][r] + 256 * accH[tt][r]);  // exact, <2^24
          // exact pow2 scalings + ONE rounding == R4's i64->double->f32 bits
          float d2v = __fadd_rn(slo[tt][r] * 0x1p-32f, shi * 0x1p-16f);
          int rowl = (r & 3) + 8 * (r >> 2) + 4 * half;          // verified C/D map
          int grow = rowtile * 128 + wv * 32 + rowl;
          D2[((size_t)(tsub * 4 + tt) * BB + grow) * HH2 + colbase] = d2v;
        }
      }
    }
  }
}

// ---- phase C: sequential v2/v3 scan over all 128 t. One block/row; one
// barrier per step (parity-buffered m2s); layer 3 redundant in all 4 waves.
__global__ __launch_bounds__(256) void phase_scan(const float* __restrict__ D2,
    const float* __restrict__ b2, const float* __restrict__ W3,
    const float* __restrict__ b3, float* __restrict__ out)
{
  __shared__ float w3t[(HH2 + 1) * CC];
  __shared__ __align__(16) ull m2s[2][4];
  __shared__ unsigned list2[4][HH2 + 8];
  const int row = blockIdx.x, tid = threadIdx.x, wv = tid >> 6, lane = tid & 63;

  for (int i = tid; i < HH2 * CC; i += 256) {
    int c = i >> 8, h2 = i & 255;                   // W3 is [c][h2]
    w3t[h2 * CC + c] = W3[i];
  }
  if (tid < CC) w3t[HH2 * CC + tid] = 0.0f;

  const float b2r = b2[tid];
  const int j3 = (lane < 3 * CC) ? (lane / CC) : 0;
  const int c3 = lane - ((lane < 3 * CC) ? j3 * CC : lane);
  const float b3r = (lane < CC) ? b3[lane] : 0.0f;

  float v2 = 0.f, v3 = 0.f, acc = 0.f;
  __syncthreads();

  float d2 = D2[(size_t)row * HH2 + tid];           // t = 0
  for (int t = 0; t < TT; ++t) {
    int tn = (t + 1 < TT) ? t + 1 : t;
    float d2n = D2[((size_t)tn * BB + row) * HH2 + tid];   // prefetch next t

    float i2 = __fadd_rn(d2, b2r);
    v2 = __fadd_rn(v2, i2);
    bool s2 = (v2 >= 1.0f);  v2 = s2 ? (v2 - 1.0f) : v2;
    ull mW = __ballot(s2);
    if (lane == 0) m2s[t & 1][wv] = mW;
    __syncthreads();                                // single barrier per step

    ull nn[4];
#pragma unroll
    for (int k = 0; k < 4; ++k) nn[k] = m2s[t & 1][k];
    int bas2[4]; int cnt2 = 0;
#pragma unroll
    for (int k = 0; k < 4; ++k) { bas2[k] = cnt2; cnt2 += (int)__popcll(nn[k]); }
#pragma unroll
    for (int k = 0; k < 4; ++k) {
      ull m = nn[k];
      if ((m >> lane) & 1ull) {
        int rank = __builtin_amdgcn_mbcnt_hi((unsigned)(m >> 32),
                   __builtin_amdgcn_mbcnt_lo((unsigned)m, 0u));
        list2[wv][bas2[k] + rank] = (unsigned)((k * 64 + lane) * W3STR);
      }
    }
    int rcnt2 = cnt2 + ((3 - (cnt2 % 3)) % 3);      // pad to x3
    if (lane < rcnt2 - cnt2) list2[wv][cnt2 + lane] = (unsigned)DUMMY2;
    __builtin_amdgcn_wave_barrier();
    __builtin_amdgcn_s_waitcnt(0xc07f);             // lgkmcnt(0), wave-local LDS
    __builtin_amdgcn_wave_barrier();

    float d3 = 0.0f;
    if (lane < 3 * CC) {                            // lane = j3*18 + c3
      for (int k = 0; k < rcnt2; k += 3) {
        unsigned o = list2[wv][k + j3];
        d3 = __fadd_rn(d3, *(const float*)((const char*)w3t + o + c3 * 4));
      }
    }
    float dA = __shfl(d3, lane + 18);
    float dB = __shfl(d3, lane + 36);
    if (lane < CC) {
      float tot = __fadd_rn(__fadd_rn(d3, dA), dB);
      float i3  = __fadd_rn(tot, b3r);
      v3 = __fadd_rn(v3, i3);
      bool s3 = (v3 >= 1.0f);  v3 = s3 ? (v3 - 1.0f) : v3;
      acc = __fadd_rn(acc, s3 ? 1.0f : 0.0f);
    }
    d2 = d2n;
  }

  if (wv == 0 && lane < CC) out[row * CC + lane] = acc * (1.0f / TT);
}

extern "C" void kernel_launch(void* const* d_in, const int* in_sizes, int n_in,
                              void* d_out, int out_size, void* d_ws, size_t ws_size,
                              hipStream_t stream)
{
  (void)in_sizes; (void)n_in; (void)out_size; (void)ws_size;
  const float* x  = (const float*)d_in[0];
  const float* W1 = (const float*)d_in[1];
  const float* b1 = (const float*)d_in[2];
  const float* W2 = (const float*)d_in[3];
  const float* b2 = (const float*)d_in[4];
  const float* W3 = (const float*)d_in[5];
  const float* b3 = (const float*)d_in[6];
  // d_in[7] = repeat (structurally 1 for this problem shape)
  float* out = (float*)d_out;
  char*  ws  = (char*)d_ws;

  signed char* dig   = (signed char*)(ws + WS_DIG);
  ull*         masks = (ull*)(ws + WS_MASK);
  float*       D2    = (float*)(ws + WS_D2);

  prep_digits<<<2048, 256, 0, stream>>>(W2, dig);
  phase_s1<<<1024, 256, 0, stream>>>(x, W1, b1, masks);
  phase_gemm<<<2048, 256, 0, stream>>>(dig, masks, D2);
  phase_scan<<<1024, 256, 0, stream>>>(D2, b2, W3, b3, out);
}

// Round 6
// 251.928 us; speedup vs baseline: 14.8955x; 1.3157x over previous
//
#include <hip/hip_runtime.h>
#include <cmath>

#define BB  1024
#define TT  128
#define HH1 512
#define HH2 256
#define CC  18

// d_ws layout (byte offsets); ws_size ~256 MiB (R4 fill evidence)
#define WS_DIG   0ull             // W2 digits: 8x4x16x2x32x16 i8 = 512 KB
#define WS_W3D   524288ull        // W3 digits LDS image: 32 KB
#define WS_MASK  557056ull        // s1 masks[t][row][8 u64] = 8 MB
#define WS_D2    8945664ull       // D2[t][row][col] fp32 = 134.2 MB
#define WS_MASK2 143163392ull     // s2 masks[t][row][4 u64] = 4 MB
#define WS_D3    147357696ull     // D3[t][row][c<18] fp32 = 9.4 MB (end ~157 MB)

typedef int  v4i  __attribute__((ext_vector_type(4)));
typedef int  v16i __attribute__((ext_vector_type(16)));
typedef unsigned long long ull;

// ---- prep: W2 fp32 -> 4 signed-i8 digit planes of llrint(w*2^32), laid out
// [stripe(8)][d(4)][s(16)][h(2)][n(32)][j(16)]; h1 = s*32+h*16+j, h2 = stripe*32+n.
__global__ __launch_bounds__(256) void prep_digits(const float* __restrict__ W2,
                                                   signed char* __restrict__ out)
{
  int i = blockIdx.x * 256 + threadIdx.x;         // [0, 524288)
  int j = i & 15, n = (i >> 4) & 31, h = (i >> 9) & 1;
  int s = (i >> 10) & 15, d = (i >> 14) & 3, st = i >> 16;
  int h1 = s * 32 + h * 16 + j;
  int h2 = st * 32 + n;
  float w = W2[h2 * HH1 + h1];
  long long ll = llrint((double)w * 4294967296.0);
  int v = (int)ll;
  signed char d0 = (signed char)(v & 255); v = (v - d0) >> 8;
  signed char d1 = (signed char)(v & 255); v = (v - d1) >> 8;
  signed char d2 = (signed char)(v & 255); v = (v - d2) >> 8;
  signed char d3 = (signed char)v;
  signed char dig = (d == 0) ? d0 : (d == 1) ? d1 : (d == 2) ? d2 : d3;
  out[i] = dig;
}

// ---- prep W3 digits, LDS image [d(4)][c8(8)][h(2)][col(32)][j(16)], 32 KB.
// h2 = c8*32 + h*16 + j; col < 18 real else zero.
__global__ __launch_bounds__(256) void prep_w3dig(const float* __restrict__ W3,
                                                  signed char* __restrict__ out)
{
  int i = blockIdx.x * 256 + threadIdx.x;         // [0, 32768)
  int j = i & 15, col = (i >> 4) & 31, h = (i >> 9) & 1;
  int c8 = (i >> 10) & 7, d = (i >> 13) & 3;
  int h2 = c8 * 32 + h * 16 + j;
  float w = (col < CC) ? W3[col * HH2 + h2] : 0.0f;
  long long ll = llrint((double)w * 4294967296.0);
  int v = (int)ll;
  signed char d0 = (signed char)(v & 255); v = (v - d0) >> 8;
  signed char d1 = (signed char)(v & 255); v = (v - d1) >> 8;
  signed char d2 = (signed char)(v & 255); v = (v - d2) >> 8;
  signed char d3 = (signed char)v;
  signed char dig = (d == 0) ? d0 : (d == 1) ? d1 : (d == 2) ? d2 : d3;
  out[i] = dig;
}

// ---- phase A: bit-exact layer-1 spike masks for all (row,t). One block/row.
__global__ __launch_bounds__(256) void phase_s1(const float* __restrict__ x,
    const float* __restrict__ W1, const float* __restrict__ b1,
    ull* __restrict__ masks)
{
  __shared__ float xrow[TT];
  int row = blockIdx.x, tid = threadIdx.x, wv = tid >> 6, lane = tid & 63;
  for (int i = tid; i < TT; i += 256) xrow[i] = x[row * TT + i];
  const float w1a = W1[tid], w1b = W1[tid + 256];
  const float b1a = b1[tid], b1b = b1[tid + 256];
  float v1a = 0.f, v1b = 0.f;
  __syncthreads();
  for (int t = 0; t < TT; ++t) {
    float xt = xrow[t];
    float iA = __fadd_rn(__fmul_rn(xt, w1a), b1a);
    v1a = __fadd_rn(v1a, iA);
    bool sA = (v1a >= 1.0f);  v1a = sA ? (v1a - 1.0f) : v1a;
    float iB = __fadd_rn(__fmul_rn(xt, w1b), b1b);
    v1b = __fadd_rn(v1b, iB);
    bool sB = (v1b >= 1.0f);  v1b = sB ? (v1b - 1.0f) : v1b;
    ull mA = __ballot(sA);
    ull mB = __ballot(sB);
    if (lane == 0) {
      ull* p = masks + ((size_t)t * BB + row) * 8;
      p[wv] = mA; p[4 + wv] = mB;
    }
  }
}

// ---- phase B: D2[t] = S1[t] @ W2^T, exact via 4 i8 digit planes.
// grid 2048 = tsub(32) x rowtile(8) x stripe(8). tt split 2x2 to cut VGPRs
// (~290 -> ~170) so 2 blocks/CU co-reside and unpack-VALU overlaps MFMA.
__global__ __launch_bounds__(256, 2) void phase_gemm(const signed char* __restrict__ Bd,
    const ull* __restrict__ masks, float* __restrict__ D2)
{
  __shared__ __align__(16) signed char Bl[65536];
  const int bid = blockIdx.x;
  const int stripe = bid & 7, rowtile = (bid >> 3) & 7, tsub = bid >> 6; // [0,32)
  const int tid = threadIdx.x, lane = tid & 63, wv = tid >> 6;
  const int half = lane >> 5;

  {
    const uint4* src = (const uint4*)(Bd + (size_t)stripe * 65536);
    uint4* dst = (uint4*)Bl;
#pragma unroll
    for (int i = 0; i < 16; ++i) dst[tid + 256 * i] = src[tid + 256 * i];
  }
  __syncthreads();

  const int arow    = rowtile * 128 + wv * 32 + (lane & 31);
  const int colbase = stripe * 32 + (lane & 31);
  const int hsh     = half * 16;
  const signed char* bbase = Bl + half * 512 + (lane & 31) * 16;

#pragma unroll
  for (int th = 0; th < 2; ++th) {                // two t-pairs
    ull words[2][8];
#pragma unroll
    for (int q = 0; q < 2; ++q) {
      const ull* mp = masks + ((size_t)(tsub * 4 + th * 2 + q) * BB + arow) * 8;
#pragma unroll
      for (int k = 0; k < 8; ++k) words[q][k] = mp[k];
    }
    float slo[2][16];
#pragma unroll
    for (int p = 0; p < 2; ++p) {
      v16i accL[2], accH[2];
#pragma unroll
      for (int q = 0; q < 2; ++q) {
        accL[q] = (v16i){0,0,0,0,0,0,0,0,0,0,0,0,0,0,0,0};
        accH[q] = (v16i){0,0,0,0,0,0,0,0,0,0,0,0,0,0,0,0};
      }
#pragma unroll
      for (int s = 0; s < 16; ++s) {
        v4i bL = *(const v4i*)(bbase + ((2 * p)     * 16 + s) * 1024);
        v4i bH = *(const v4i*)(bbase + ((2 * p + 1) * 16 + s) * 1024);
#pragma unroll
        for (int q = 0; q < 2; ++q) {
          unsigned bits = (unsigned)(words[q][s >> 1] >> (((s & 1) << 5) + hsh)) & 0xFFFFu;
          v4i a;
          a.x = (int)((( bits        & 15u) * 0x204081u) & 0x01010101u);
          a.y = (int)((((bits >>  4) & 15u) * 0x204081u) & 0x01010101u);
          a.z = (int)((((bits >>  8) & 15u) * 0x204081u) & 0x01010101u);
          a.w = (int)((((bits >> 12) & 15u) * 0x204081u) & 0x01010101u);
          accL[q] = __builtin_amdgcn_mfma_i32_32x32x32_i8(a, bL, accL[q], 0, 0, 0);
          accH[q] = __builtin_amdgcn_mfma_i32_32x32x32_i8(a, bH, accH[q], 0, 0, 0);
        }
      }
      if (p == 0) {
#pragma unroll
        for (int q = 0; q < 2; ++q)
#pragma unroll
          for (int r = 0; r < 16; ++r)
            slo[q][r] = (float)(accL[q][r] + 256 * accH[q][r]);   // exact < 2^24
      } else {
#pragma unroll
        for (int q = 0; q < 2; ++q) {
#pragma unroll
          for (int r = 0; r < 16; ++r) {
            float shi = (float)(accL[q][r] + 256 * accH[q][r]);   // exact < 2^24
            float d2v = __fadd_rn(slo[q][r] * 0x1p-32f, shi * 0x1p-16f);
            int rowl = (r & 3) + 8 * (r >> 2) + 4 * half;
            int grow = rowtile * 128 + wv * 32 + rowl;
            D2[((size_t)(tsub * 4 + th * 2 + q) * BB + grow) * HH2 + colbase] = d2v;
          }
        }
      }
    }
  }
}

// ---- C1: v2 scan -> s2 masks. thread=(row,col); no barriers, no LDS.
__global__ __launch_bounds__(256) void phase_s2scan(const float* __restrict__ D2,
    const float* __restrict__ b2, ull* __restrict__ masks2)
{
  const int row = blockIdx.x, tid = threadIdx.x, wv = tid >> 6, lane = tid & 63;
  const float b2r = b2[tid];
  const float* p = D2 + (size_t)row * HH2 + tid;
  float v2 = 0.f;
  float d2 = p[0];
  for (int t = 0; t < TT; ++t) {
    int tn = (t + 1 < TT) ? t + 1 : t;
    float d2n = p[(size_t)tn * (BB * HH2)];       // prefetch next t
    float i2 = __fadd_rn(d2, b2r);
    v2 = __fadd_rn(v2, i2);
    bool s2 = (v2 >= 1.0f);  v2 = s2 ? (v2 - 1.0f) : v2;
    ull m = __ballot(s2);
    if (lane == 0) masks2[((size_t)t * BB + row) * 4 + wv] = m;
    d2 = d2n;
  }
}

// ---- C2: D3[t] = S2[t] @ W3^T, exact i8 MFMA. Block: 32 rows x 4 t.
// grid 1024 = tgrp(32) x rowtile(32). B slab 32 KB in LDS.
__global__ __launch_bounds__(256) void phase_l3(const signed char* __restrict__ W3d,
    const ull* __restrict__ masks2, float* __restrict__ D3)
{
  __shared__ __align__(16) signed char Bl[32768];
  const int bid = blockIdx.x;
  const int rowtile = bid & 31, tgrp = bid >> 5;
  const int tid = threadIdx.x, lane = tid & 63, wv = tid >> 6;
  const int half = lane >> 5;
  const int t = tgrp * 4 + wv;
  const int row = rowtile * 32 + (lane & 31);

  {
    const uint4* src = (const uint4*)W3d;
    uint4* dst = (uint4*)Bl;
#pragma unroll
    for (int i = 0; i < 8; ++i) dst[tid + 256 * i] = src[tid + 256 * i];
  }

  ull words[4];
  {
    const ull* mp = masks2 + ((size_t)t * BB + row) * 4;
#pragma unroll
    for (int k = 0; k < 4; ++k) words[k] = mp[k];
  }
  __syncthreads();

  const signed char* bbase = Bl + half * 512 + (lane & 31) * 16;
  v16i acc[4];
#pragma unroll
  for (int d = 0; d < 4; ++d) acc[d] = (v16i){0,0,0,0,0,0,0,0,0,0,0,0,0,0,0,0};

#pragma unroll
  for (int c8 = 0; c8 < 8; ++c8) {
    unsigned bits = (unsigned)(words[c8 >> 1] >> (((c8 & 1) << 5) + half * 16)) & 0xFFFFu;
    v4i a;
    a.x = (int)((( bits        & 15u) * 0x204081u) & 0x01010101u);
    a.y = (int)((((bits >>  4) & 15u) * 0x204081u) & 0x01010101u);
    a.z = (int)((((bits >>  8) & 15u) * 0x204081u) & 0x01010101u);
    a.w = (int)((((bits >> 12) & 15u) * 0x204081u) & 0x01010101u);
#pragma unroll
    for (int d = 0; d < 4; ++d) {
      v4i b = *(const v4i*)(bbase + ((d * 8 + c8) * 2) * 512);
      acc[d] = __builtin_amdgcn_mfma_i32_32x32x32_i8(a, b, acc[d], 0, 0, 0);
    }
  }

  const int col = lane & 31;
#pragma unroll
  for (int r = 0; r < 16; ++r) {
    float slo = (float)(acc[0][r] + 256 * acc[1][r]);   // exact < 2^24
    float shi = (float)(acc[2][r] + 256 * acc[3][r]);   // exact < 2^24
    float d3v = __fadd_rn(slo * 0x1p-32f, shi * 0x1p-16f);
    int rowl = (r & 3) + 8 * (r >> 2) + 4 * half;
    int grow = rowtile * 32 + rowl;
    if (col < CC) D3[((size_t)t * BB + grow) * CC + col] = d3v;
  }
}

// ---- C3: v3/acc scan + output. thread=(row,c); coalesced; grid 72.
__global__ __launch_bounds__(256) void phase_v3(const float* __restrict__ D3,
    const float* __restrict__ b3, float* __restrict__ out)
{
  int g = blockIdx.x * 256 + threadIdx.x;         // [0, 18432)
  int row = g / CC, c = g - row * CC;
  const float b3r = b3[c];
  float v3 = 0.f, acc = 0.f;
  float d3 = D3[g];
  for (int t = 0; t < TT; ++t) {
    int tn = (t + 1 < TT) ? t + 1 : t;
    float d3n = D3[(size_t)tn * (BB * CC) + g];   // prefetch
    float i3 = __fadd_rn(d3, b3r);
    v3 = __fadd_rn(v3, i3);
    bool s3 = (v3 >= 1.0f);  v3 = s3 ? (v3 - 1.0f) : v3;
    acc = __fadd_rn(acc, s3 ? 1.0f : 0.0f);
    d3 = d3n;
  }
  out[g] = acc * (1.0f / TT);
}

extern "C" void kernel_launch(void* const* d_in, const int* in_sizes, int n_in,
                              void* d_out, int out_size, void* d_ws, size_t ws_size,
                              hipStream_t stream)
{
  (void)in_sizes; (void)n_in; (void)out_size; (void)ws_size;
  const float* x  = (const float*)d_in[0];
  const float* W1 = (const float*)d_in[1];
  const float* b1 = (const float*)d_in[2];
  const float* W2 = (const float*)d_in[3];
  const float* b2 = (const float*)d_in[4];
  const float* W3 = (const float*)d_in[5];
  const float* b3 = (const float*)d_in[6];
  // d_in[7] = repeat (structurally 1 for this problem shape)
  float* out = (float*)d_out;
  char*  ws  = (char*)d_ws;

  signed char* dig    = (signed char*)(ws + WS_DIG);
  signed char* w3dig  = (signed char*)(ws + WS_W3D);
  ull*         masks  = (ull*)(ws + WS_MASK);
  float*       D2     = (float*)(ws + WS_D2);
  ull*         masks2 = (ull*)(ws + WS_MASK2);
  float*       D3     = (float*)(ws + WS_D3);

  prep_digits<<<2048, 256, 0, stream>>>(W2, dig);
  prep_w3dig<<<128, 256, 0, stream>>>(W3, w3dig);
  phase_s1<<<1024, 256, 0, stream>>>(x, W1, b1, masks);
  phase_gemm<<<2048, 256, 0, stream>>>(dig, masks, D2);
  phase_s2scan<<<1024, 256, 0, stream>>>(D2, b2, masks2);
  phase_l3<<<1024, 256, 0, stream>>>(w3dig, masks2, D3);
  phase_v3<<<72, 256, 0, stream>>>(D3, b3, out);
}